// Round 1
// 370.059 us; speedup vs baseline: 1.0836x; 1.0836x over previous
//
#include <hip/hip_runtime.h>
#include <math.h>

#define N_NODES 100000
#define N_EDGES 100000
#define NNZT    1600000
#define C       128
#define NB      ((N_NODES + 255) >> 8)    // 391 node-buckets of 256 nodes
#define EPB     8192                      // edges per binA block

typedef _Float16 half8 __attribute__((ext_vector_type(8)));
typedef _Float16 h2    __attribute__((ext_vector_type(2)));
typedef float    f32x4 __attribute__((ext_vector_type(4)));

// K1: t_node[i] = dot(x_0[i], a_tgt); also emit x0h = (fp16)x0.
// One wave per node row (64 lanes x float2), no LDS, no barriers.
__global__ __launch_bounds__(256) void k1_node_dot(
    const float* __restrict__ x0, const float* __restrict__ att,
    float* __restrict__ t_node, _Float16* __restrict__ x0h)
{
    int wave = threadIdx.x >> 6;
    int lane = threadIdx.x & 63;
    int node = blockIdx.x * 4 + wave;          // 100000 % 4 == 0
    const float2 xv = *reinterpret_cast<const float2*>(x0 + (size_t)node * C + lane * 2);
    h2 hx = { (_Float16)xv.x, (_Float16)xv.y };
    *reinterpret_cast<h2*>(x0h + (size_t)node * C + lane * 2) = hx;
    const float2 av = *reinterpret_cast<const float2*>(att + C + lane * 2);
    float v = xv.x * av.x + xv.y * av.y;
    #pragma unroll
    for (int off = 32; off > 0; off >>= 1) v += __shfl_xor(v, off, 64);
    if (lane == 0) t_node[node] = v;
}

// RP: edge row pointer from sorted edge_idx, atomic-free one pass.
__global__ __launch_bounds__(256) void k_rowptr(
    const int* __restrict__ edge_idx, int* __restrict__ row_start)
{
    int e = blockIdx.x * 256 + threadIdx.x;
    if (e >= NNZT) return;
    int j = edge_idx[e];
    int jprev = (e == 0) ? -1 : edge_idx[e - 1];
    for (int k = jprev + 1; k <= j; ++k) row_start[k] = e;
    if (e == NNZT - 1)
        for (int k = j + 1; k <= N_EDGES; ++k) row_start[k] = NNZT;
}

// WC: Wt[n][k] = (fp16) W[k][n]  (transposed fp16 weight for MFMA B-frags)
__global__ __launch_bounds__(256) void k_wcvt(
    const float* __restrict__ W, _Float16* __restrict__ wt)
{
    int i = blockIdx.x * 256 + threadIdx.x;   // 16384
    int k = i >> 7, n = i & 127;
    wt[(size_t)n * C + k] = (_Float16)W[(size_t)k * C + n];
}

// K2: segment sum -> m01h row (fp16) + s_edge dot, via row_start.
// ONE WAVE PER ROW: 4 edge-slots x 16 lanes x half8. Cross-slot reduce via
// two shfl_xor steps (lane^16, lane^32). No LDS, no __syncthreads -> the
// gather latency is hidden across 4 independent waves per block instead of
// being drained twice per row at barriers.
__global__ __launch_bounds__(256) void k2_edge_msg(
    const half8* __restrict__ x0h,
    const int*   __restrict__ node_idx,
    const int*   __restrict__ row_start,
    const float* __restrict__ values,
    const float* __restrict__ att,
    _Float16* __restrict__ m01h,
    float* __restrict__ s_edge)
{
    int wave = threadIdx.x >> 6;
    int lane = threadIdx.x & 63;
    int j    = blockIdx.x * 4 + wave;          // 100000 % 4 == 0
    int sub  = lane >> 4;                      // 0..3 edge slot
    int ln   = lane & 15;                      // half8 chunk of the row
    int start = row_start[j];
    int end   = row_start[j + 1];

    h2 hacc[4];
    #pragma unroll
    for (int q = 0; q < 4; ++q) hacc[q] = (h2){(_Float16)0.f, (_Float16)0.f};

    int e = start + sub;
    for (; e + 4 < end; e += 8) {
        int   n0 = node_idx[e];
        int   n1 = node_idx[e + 4];
        _Float16 v0 = (_Float16)values[e];
        _Float16 v1 = (_Float16)values[e + 4];
        h2 v0p = {v0, v0}, v1p = {v1, v1};
        half8 A = x0h[(size_t)n0 * 16 + ln];
        half8 B = x0h[(size_t)n1 * 16 + ln];
        const h2* a2 = reinterpret_cast<const h2*>(&A);
        const h2* b2 = reinterpret_cast<const h2*>(&B);
        #pragma unroll
        for (int q = 0; q < 4; ++q)
            hacc[q] = a2[q] * v0p + (b2[q] * v1p + hacc[q]);
    }
    if (e < end) {
        int   n0 = node_idx[e];
        _Float16 v0 = (_Float16)values[e];
        h2 v0p = {v0, v0};
        half8 A = x0h[(size_t)n0 * 16 + ln];
        const h2* a2 = reinterpret_cast<const h2*>(&A);
        #pragma unroll
        for (int q = 0; q < 4; ++q) hacc[q] = a2[q] * v0p + hacc[q];
    }

    // f32 cross-slot reduction, all in-wave.
    float f[8];
    #pragma unroll
    for (int q = 0; q < 4; ++q) {
        f[2 * q]     = (float)hacc[q][0];
        f[2 * q + 1] = (float)hacc[q][1];
    }
    #pragma unroll
    for (int q = 0; q < 8; ++q) {
        f[q] += __shfl_xor(f[q], 16, 64);
        f[q] += __shfl_xor(f[q], 32, 64);
    }
    // every lane now holds the total for its ln-chunk (replicated across subs)
    if (lane < 16) {
        half8 hv;
        #pragma unroll
        for (int q = 0; q < 8; ++q) hv[q] = (_Float16)f[q];
        reinterpret_cast<half8*>(m01h + (size_t)j * C)[ln] = hv;
    }
    // s_edge[j] = dot(m01 row, a_src)
    f32x4 a0 = *reinterpret_cast<const f32x4*>(att + ln * 8);
    f32x4 a1 = *reinterpret_cast<const f32x4*>(att + ln * 8 + 4);
    float p = f[0] * a0[0] + f[1] * a0[1] + f[2] * a0[2] + f[3] * a0[3]
            + f[4] * a1[0] + f[5] * a1[1] + f[6] * a1[2] + f[7] * a1[3];
    #pragma unroll
    for (int off = 8; off > 0; off >>= 1) p += __shfl_xor(p, off, 64);
    if (lane == 0) s_edge[j] = p;
}

// BH: per-bucket totals. Wave-private LDS histograms -> ~100k global adds.
__global__ __launch_bounds__(256) void k_bhist(
    const int* __restrict__ node_idx, int* __restrict__ btot)
{
    __shared__ int cnt4[4][NB];
    int tid = threadIdx.x;
    int w   = tid >> 6;
    for (int b = tid; b < 4 * NB; b += 256) (&cnt4[0][0])[b] = 0;
    __syncthreads();
    const int per = (NNZT + 255) / 256;   // 6250
    int e0 = blockIdx.x * per;
    int e1 = e0 + per; if (e1 > NNZT) e1 = NNZT;
    for (int e = e0 + tid; e < e1; e += 256)
        atomicAdd(&cnt4[w][node_idx[e] >> 8], 1);
    __syncthreads();
    for (int b = tid; b < NB; b += 256) {
        int cc = cnt4[0][b] + cnt4[1][b] + cnt4[2][b] + cnt4[3][b];
        if (cc) atomicAdd(&btot[b], cc);
    }
}

// BS: exclusive scan of 391 bucket totals -> bbase[0..NB], bcur init.
__global__ __launch_bounds__(512) void k_bscan(
    const int* __restrict__ btot, int* __restrict__ bbase, int* __restrict__ bcur)
{
    __shared__ int s[512];
    int tid = threadIdx.x;
    int v = (tid < NB) ? btot[tid] : 0;
    s[tid] = v;
    __syncthreads();
    for (int off = 1; off < 512; off <<= 1) {
        int t = (tid >= off) ? s[tid - off] : 0;
        __syncthreads();
        s[tid] += t;
        __syncthreads();
    }
    if (tid < NB) { bbase[tid] = s[tid] - v; bcur[tid] = s[tid] - v; }
    if (tid == NB - 1) bbase[NB] = s[tid];
}

// BinA: chunk-reserve scatter into bucket-ordered tmp arrays.
__global__ __launch_bounds__(256) void k_binA(
    const int*   __restrict__ node_idx,
    const int*   __restrict__ edge_idx,
    const float* __restrict__ values,
    const float* __restrict__ s_edge,
    const float* __restrict__ t_node,
    int*  __restrict__ bcur,
    int*  __restrict__ tmp_n,
    int2* __restrict__ tmp_jc)
{
    __shared__ int cnt4[4][NB];
    __shared__ int res4[4][NB];
    int tid = threadIdx.x;
    int w   = tid >> 6;
    for (int b = tid; b < 4 * NB; b += 256) (&cnt4[0][0])[b] = 0;
    __syncthreads();
    int e0 = blockIdx.x * EPB;
    int e1 = e0 + EPB; if (e1 > NNZT) e1 = NNZT;
    for (int e = e0 + tid; e < e1; e += 256)
        atomicAdd(&cnt4[w][node_idx[e] >> 8], 1);
    __syncthreads();
    for (int b = tid; b < NB; b += 256) {
        int c0 = cnt4[0][b], c1 = cnt4[1][b], c2 = cnt4[2][b], c3 = cnt4[3][b];
        int tot = c0 + c1 + c2 + c3;
        int r = tot ? atomicAdd(&bcur[b], tot) : 0;
        res4[0][b] = r;
        res4[1][b] = r + c0;
        res4[2][b] = r + c0 + c1;
        res4[3][b] = r + c0 + c1 + c2;
        cnt4[0][b] = 0; cnt4[1][b] = 0; cnt4[2][b] = 0; cnt4[3][b] = 0;
    }
    __syncthreads();
    for (int e = e0 + tid; e < e1; e += 256) {
        int n = node_idx[e];
        int b = n >> 8;
        int r = atomicAdd(&cnt4[w][b], 1);
        int pos = res4[w][b] + r;
        int j = edge_idx[e];
        float s = s_edge[j] + t_node[n];
        float coef = (s > 0.f ? s : expm1f(s)) * values[e];
        tmp_n[pos]  = n;
        tmp_jc[pos] = make_int2(j, __float_as_int(coef));
    }
}

// BinB: one block per bucket. Local LDS hist+scan derives per-node base/count
// (written out for k3), then scatters to exact per-node slots.
__global__ __launch_bounds__(256) void k_binB(
    const int*  __restrict__ tmp_n,
    const int2* __restrict__ tmp_jc,
    const int*  __restrict__ bbase,
    int*  __restrict__ base,
    int*  __restrict__ count,
    int2* __restrict__ jc)
{
    int b   = blockIdx.x;
    int tid = threadIdx.x;
    int n0  = b << 8;
    __shared__ int cnt[256], scn[256], cur[256];
    __shared__ int lo_s, hi_s;
    cnt[tid] = 0;
    if (tid == 0) { lo_s = bbase[b]; hi_s = bbase[b + 1]; }
    __syncthreads();
    int lo = lo_s, hi = hi_s;
    for (int i = lo + tid; i < hi; i += 256)
        atomicAdd(&cnt[tmp_n[i] - n0], 1);
    __syncthreads();
    int v = cnt[tid];
    scn[tid] = v;
    __syncthreads();
    for (int off = 1; off < 256; off <<= 1) {
        int t = (tid >= off) ? scn[tid - off] : 0;
        __syncthreads();
        scn[tid] += t;
        __syncthreads();
    }
    int excl = scn[tid] - v;
    int nn = n0 + tid;
    if (nn < N_NODES) { base[nn] = lo + excl; count[nn] = v; }
    cur[tid] = lo + excl;
    __syncthreads();
    for (int i = lo + tid; i < hi; i += 256) {
        int n = tmp_n[i];
        int pos = atomicAdd(&cur[n - n0], 1);
        jc[pos] = tmp_jc[i];
    }
}

// K3: gather-accumulate per destination node (atomic-free), fp16 rows.
// ONE WAVE PER NODE, same structure as k2: 4 slots x 16 lanes x half8,
// shfl_xor cross-slot reduce, no LDS/barriers.
__global__ __launch_bounds__(256) void k3_gather(
    const half8* __restrict__ m01h,
    const int2*  __restrict__ jc,
    const int*   __restrict__ base,
    const int*   __restrict__ count,
    _Float16* __restrict__ yh)
{
    int wave = threadIdx.x >> 6;
    int lane = threadIdx.x & 63;
    int n    = blockIdx.x * 4 + wave;          // 100000 % 4 == 0
    int sub  = lane >> 4;
    int ln   = lane & 15;
    int b    = base[n];
    int cnt  = count[n];

    float facc[8];
    #pragma unroll
    for (int q = 0; q < 8; ++q) facc[q] = 0.f;

    int i = sub;
    for (; i + 4 < cnt; i += 8) {
        int2 p0 = jc[b + i];
        int2 p1 = jc[b + i + 4];
        float c0 = __int_as_float(p0.y);
        float c1 = __int_as_float(p1.y);
        half8 a  = m01h[(size_t)p0.x * 16 + ln];
        half8 bb = m01h[(size_t)p1.x * 16 + ln];
        #pragma unroll
        for (int q = 0; q < 8; ++q)
            facc[q] += c0 * (float)a[q] + c1 * (float)bb[q];
    }
    if (i < cnt) {
        int2 p0 = jc[b + i];
        float c0 = __int_as_float(p0.y);
        half8 a = m01h[(size_t)p0.x * 16 + ln];
        #pragma unroll
        for (int q = 0; q < 8; ++q) facc[q] += c0 * (float)a[q];
    }

    #pragma unroll
    for (int q = 0; q < 8; ++q) {
        facc[q] += __shfl_xor(facc[q], 16, 64);
        facc[q] += __shfl_xor(facc[q], 32, 64);
    }
    if (lane < 16) {
        half8 hv;
        #pragma unroll
        for (int q = 0; q < 8; ++q) hv[q] = (_Float16)facc[q];
        reinterpret_cast<half8*>(yh + (size_t)n * C)[ln] = hv;
    }
}

// K4: out = yh @ W via MFMA f16. One wave per 16 rows; 8 col-tiles x 4 k-chunks.
__global__ __launch_bounds__(64) void k4_mfma(
    const _Float16* __restrict__ yh,   // N_NODES x C row-major
    const _Float16* __restrict__ wt,   // wt[n*C+k] = W[k][n]
    float* __restrict__ out)
{
    int lane = threadIdx.x;            // 0..63
    int m    = lane & 15;
    int quad = lane >> 4;              // 0..3
    int rb   = blockIdx.x * 16;
    const _Float16* yrow = yh + (size_t)(rb + m) * C + quad * 8;
    half8 a[4];
    #pragma unroll
    for (int kc = 0; kc < 4; ++kc)
        a[kc] = *reinterpret_cast<const half8*>(yrow + kc * 32);
    #pragma unroll
    for (int ct = 0; ct < 8; ++ct) {
        const _Float16* wrow = wt + (size_t)(ct * 16 + m) * C + quad * 8;
        f32x4 acc = {0.f, 0.f, 0.f, 0.f};
        #pragma unroll
        for (int kc = 0; kc < 4; ++kc) {
            half8 b = *reinterpret_cast<const half8*>(wrow + kc * 32);
            acc = __builtin_amdgcn_mfma_f32_16x16x32_f16(a[kc], b, acc, 0, 0, 0);
        }
        int orow = rb + quad * 4;
        int ocol = ct * 16 + m;
        #pragma unroll
        for (int r = 0; r < 4; ++r)
            out[(size_t)(orow + r) * C + ocol] = acc[r];
    }
}

extern "C" void kernel_launch(void* const* d_in, const int* in_sizes, int n_in,
                              void* d_out, int out_size, void* d_ws, size_t ws_size,
                              hipStream_t stream)
{
    const float* x0       = (const float*)d_in[0];
    const int*   node_idx = (const int*)  d_in[1];
    const int*   edge_idx = (const int*)  d_in[2];
    const float* values   = (const float*)d_in[3];
    const float* W        = (const float*)d_in[4];
    const float* att      = (const float*)d_in[5];
    float* out = (float*)d_out;

    // d_out layout: [x0h 25.6MB][m01h 25.6MB]. x0h dead after k2 -> reused for
    // binning temporaries (19.2 MB). All dead before k4 writes final output.
    _Float16* x0h_s  = (_Float16*)d_out;
    _Float16* m01h_s = x0h_s + (size_t)N_NODES * C;
    int*  tmp_n  = (int*)d_out;                               // 6.4 MB
    int2* tmp_jc = (int2*)((char*)d_out + (size_t)NNZT * 4);  // 12.8 MB

    char*  p   = (char*)d_ws;
    _Float16* yh    = (_Float16*)p; p += (size_t)N_NODES * C * sizeof(_Float16); // 25.6 MB
    float* t_node   = (float*)p;  p += N_NODES * sizeof(float);
    float* s_edge   = (float*)p;  p += N_EDGES * sizeof(float);
    int*   count    = (int*)p;    p += N_NODES * sizeof(int);
    int*   base     = (int*)p;    p += N_NODES * sizeof(int);
    int*   btot     = (int*)p;    p += 512 * sizeof(int);
    int*   bbase    = (int*)p;    p += 512 * sizeof(int);
    int*   bcur     = (int*)p;    p += 512 * sizeof(int);
    int*   row_start= (int*)p;    p += (N_EDGES + 1) * sizeof(int);
    _Float16* wt    = (_Float16*)p; p += (size_t)C * C * sizeof(_Float16);       // 32 KB
    int2*  jc       = (int2*)p;   p += (size_t)NNZT * sizeof(int2);              // 12.8 MB

    hipMemsetAsync(btot, 0, NB * sizeof(int), stream);

    k1_node_dot<<<N_NODES / 4, 256, 0, stream>>>(x0, att, t_node, x0h_s);
    k_rowptr<<<(NNZT + 255) / 256, 256, 0, stream>>>(edge_idx, row_start);
    k_wcvt  <<<(C * C + 255) / 256, 256, 0, stream>>>(W, wt);
    k2_edge_msg<<<N_EDGES / 4, 256, 0, stream>>>((const half8*)x0h_s, node_idx, row_start,
                                                 values, att, m01h_s, s_edge);

    k_bhist<<<256, 256, 0, stream>>>(node_idx, btot);
    k_bscan<<<1, 512, 0, stream>>>(btot, bbase, bcur);
    k_binA<<<(NNZT + EPB - 1) / EPB, 256, 0, stream>>>(node_idx, edge_idx, values,
                                                       s_edge, t_node, bcur, tmp_n, tmp_jc);
    k_binB<<<NB, 256, 0, stream>>>(tmp_n, tmp_jc, bbase, base, count, jc);

    k3_gather<<<N_NODES / 4, 256, 0, stream>>>((const half8*)m01h_s, jc, base, count, yh);
    k4_mfma<<<N_NODES / 16, 64, 0, stream>>>(yh, wt, out);
}